// Round 7
// baseline (799.034 us; speedup 1.0000x reference)
//
#include <hip/hip_runtime.h>
#include <hip/hip_fp16.h>

// GraphEncoder: node linear; 3x GINEConv(eps=0, nn=Linear+LeakyReLU); skip; head Linear+LayerNorm.
// R15: two bit-identical transforms (the precision cliff forbids any rounding change):
//  (1) 8-edge unroll in gather: 8-body = two verbatim 4-bodies (same fp add association), but all
//      8 random nbr gathers issue first -> 8 VMEM in flight (was 4). a16 scalar stream consumed
//      in two 4-edge chunks to stay within SGPR budget.
//  (2) head fused into layer-2: phase 2 writes the h tile to LDS (not global); wave 0 then runs
//      exactly one R10-k_head wave body for the block's 16 rows (same frags, same t=s+h+l order,
//      same MFMA chain, same shfl LN reduce -> bit-identical). Kills hA write + head re-read +
//      one dispatch. Ping-pong reordered: L0 skip->B(d_out), L1 B->A(ws), L2 A->head->out(d_out);
//      d_out(B) is dead when the head writes it.
// edge_index arrives as int32 (harness converts int64 inputs).
constexpr int N      = 100000;
constexpr int E      = 1600000;
constexpr int F_IN   = 64;
constexpr int F_EDGE = 16;
constexpr int H      = 128;
constexpr int NB     = (N + 255) / 256;     // 391 scan blocks
constexpr float NEG  = 0.01f;
constexpr float EPS  = 1e-5f;

typedef _Float16 hv2   __attribute__((ext_vector_type(2)));
typedef _Float16 f16x8 __attribute__((ext_vector_type(8)));
typedef float    f32x4 __attribute__((ext_vector_type(4)));

// ================= CSR build =================
__global__ __launch_bounds__(256) void k_zero(int* __restrict__ p, int n) {
  int i = blockIdx.x * 256 + threadIdx.x;
  if (i < n) p[i] = 0;
}

__global__ __launch_bounds__(256) void k_hist(const int* __restrict__ eidx, int* __restrict__ deg) {
  int i = blockIdx.x * 256 + threadIdx.x;
  if (i < E) atomicAdd(&deg[eidx[E + i]], 1);
}

__global__ __launch_bounds__(256) void k_scan_block(const int* __restrict__ deg,
    int* __restrict__ excl, int* __restrict__ bsum) {
  __shared__ int s[256];
  int t = threadIdx.x, i = blockIdx.x * 256 + t;
  int v = (i < N) ? deg[i] : 0;
  s[t] = v; __syncthreads();
#pragma unroll
  for (int off = 1; off < 256; off <<= 1) {
    int u = (t >= off) ? s[t - off] : 0;
    __syncthreads();
    s[t] += u;
    __syncthreads();
  }
  if (i < N) excl[i] = s[t] - v;
  if (t == 255) bsum[blockIdx.x] = s[255];
}

__global__ __launch_bounds__(512) void k_scan_top(const int* __restrict__ bsum, int* __restrict__ boff) {
  __shared__ int s[512];
  int t = threadIdx.x;
  int v = (t < NB) ? bsum[t] : 0;
  s[t] = v; __syncthreads();
#pragma unroll
  for (int off = 1; off < 512; off <<= 1) {
    int u = (t >= off) ? s[t - off] : 0;
    __syncthreads();
    s[t] += u;
    __syncthreads();
  }
  if (t < NB) boff[t] = s[t] - v;
}

__global__ __launch_bounds__(256) void k_scan_add(const int* __restrict__ excl,
    const int* __restrict__ boff, int* __restrict__ rowptr, int* __restrict__ cursor) {
  int i = blockIdx.x * 256 + threadIdx.x;
  if (i < N) {
    int r = excl[i] + boff[i >> 8];
    rowptr[i] = r;
    cursor[i] = r;
  }
}

// scatter: CSR-slot src index + edge_attr row converted to fp16 (2x uint4 = 32B/edge)
__global__ __launch_bounds__(256) void k_scatter(const int* __restrict__ eidx,
    const float* __restrict__ edge_attr, int* __restrict__ cursor,
    int* __restrict__ csr_src, uint4* __restrict__ csr_a16) {
  int i = blockIdx.x * 256 + threadIdx.x;
  if (i >= E) return;
  int d = eidx[E + i];
  int pos = atomicAdd(&cursor[d], 1);
  csr_src[pos] = eidx[i];
  const float4* ar = (const float4*)(edge_attr + (size_t)i * F_EDGE);
  float4 f0 = ar[0], f1 = ar[1], f2 = ar[2], f3 = ar[3];
  __half2 hh[8];
  hh[0] = __float22half2_rn(make_float2(f0.x, f0.y));
  hh[1] = __float22half2_rn(make_float2(f0.z, f0.w));
  hh[2] = __float22half2_rn(make_float2(f1.x, f1.y));
  hh[3] = __float22half2_rn(make_float2(f1.z, f1.w));
  hh[4] = __float22half2_rn(make_float2(f2.x, f2.y));
  hh[5] = __float22half2_rn(make_float2(f2.z, f2.w));
  hh[6] = __float22half2_rn(make_float2(f3.x, f3.y));
  hh[7] = __float22half2_rn(make_float2(f3.z, f3.w));
  const uint4* u = (const uint4*)hh;
  csr_a16[2 * (size_t)pos + 0] = u[0];
  csr_a16[2 * (size_t)pos + 1] = u[1];
}

// ================= weight pack -> MFMA B-frag fp16 hi/lo =================
// mats 0..2 (W_conv[l]): element = W[ks*32+(lane>>4)*8+e][(lane&15)*8 + ct] (coalesced epilogue).
// mat 3 (W_head): R10 layout, element = W[ks*32+(lane>>4)*8+e][ct*16 + (lane&15)]
//   (head phase is the R10 k_head wave body verbatim -> LN order bit-identical).
// half index = ((ks*8+ct)*64 + lane)*8 + e.
__global__ __launch_bounds__(256) void k_pack_w(
    const float* __restrict__ W_conv, const float* __restrict__ W_head,
    __half* __restrict__ Wp_hi, __half* __restrict__ Wp_lo) {
  int t = blockIdx.x * 256 + threadIdx.x;     // [0, 4*16384)
  int mat = t >> 14;
  int r = t & 16383;
  int e = r & 7, lane = (r >> 3) & 63, ct = (r >> 9) & 7, ks = (r >> 12) & 3;
  int k = ks * 32 + (lane >> 4) * 8 + e;
  int col = (mat < 3) ? ((lane & 15) * 8 + ct) : (ct * 16 + (lane & 15));
  const float* src = (mat < 3) ? (W_conv + (size_t)mat * H * H) : W_head;
  float v = src[k * H + col];
  __half hi = __float2half(v);
  __half lo = __float2half(v - __half2float(hi));
  Wp_hi[t] = hi;
  Wp_lo[t] = lo;
}

// ================= node linear (fp32, R10 lineage): skip = x @ W_node + b, fp16 hi out =================
__global__ __launch_bounds__(256) void k_node_linear(
    const float* __restrict__ x, const float* __restrict__ W,
    const float* __restrict__ b, __half* __restrict__ skip_hi) {
  __shared__ float xs[32][F_IN];             // 8 KB
  int i0 = blockIdx.x * 32;
  {
    const float4* s4 = (const float4*)(x + (size_t)i0 * F_IN);
    float4* t4 = (float4*)xs;
#pragma unroll
    for (int r = 0; r < 2; ++r) t4[threadIdx.x + 256 * r] = s4[threadIdx.x + 256 * r];
  }
  __syncthreads();
  int c0 = (threadIdx.x & 31) * 4;
  int n0 = (threadIdx.x >> 5) * 4;
  float4 bb = *(const float4*)(b + c0);
  float4 acc[4] = {bb, bb, bb, bb};
#pragma unroll 4
  for (int k = 0; k < F_IN; ++k) {
    float4 w4 = *(const float4*)(W + k * H + c0);   // coalesced; reused by 4 nodes
#pragma unroll
    for (int j = 0; j < 4; ++j) {
      float s = xs[n0 + j][k];                      // LDS broadcast
      acc[j].x = fmaf(s, w4.x, acc[j].x);
      acc[j].y = fmaf(s, w4.y, acc[j].y);
      acc[j].z = fmaf(s, w4.z, acc[j].z);
      acc[j].w = fmaf(s, w4.w, acc[j].w);
    }
  }
#pragma unroll
  for (int j = 0; j < 4; ++j) {
    size_t idx = (size_t)(i0 + n0 + j) * H + c0;
    __half2* ph = (__half2*)(skip_hi + idx);
    ph[0] = __float22half2_rn(make_float2(acc[j].x, acc[j].y));
    ph[1] = __float22half2_rn(make_float2(acc[j].z, acc[j].w));
  }
}

// ================= shared gather helpers =================
__device__ __forceinline__ void dot16(uint4 A0, uint4 A1,
                                      const hv2* __restrict__ wA, const hv2* __restrict__ wB,
                                      float& tx, float& ty) {
  unsigned u[8] = {A0.x, A0.y, A0.z, A0.w, A1.x, A1.y, A1.z, A1.w};
#pragma unroll
  for (int j = 0; j < 8; ++j) {
    hv2 a = __builtin_bit_cast(hv2, u[j]);
    tx = __builtin_amdgcn_fdot2(a, wA[j], tx, false);
    ty = __builtin_amdgcn_fdot2(a, wB[j], ty, false);
  }
}

// One node's gather: self + sum_in relu(nbr + a16@We + be). R13 arithmetic verbatim; the 8-edge
// block equals two successive 4-edge bodies (same add association) with all 8 gathers in flight.
__device__ __forceinline__ float2 gather_node(
    int node, int lane,
    const int* __restrict__ rowptr, const int* __restrict__ deg,
    const int* __restrict__ csr_src, const uint4* __restrict__ csr_a16,
    const __half2* __restrict__ nbr,
    const __half2* __restrict__ self_hi, const __half2* __restrict__ self_lo,
    float2 bias, const hv2* wA, const hv2* wB) {
  float2 acc;
  {
    float2 a = __half22float2(self_hi[(size_t)node * 64 + lane]);
    if (self_lo) {                           // wave-uniform scalar branch
      float2 l = __half22float2(self_lo[(size_t)node * 64 + lane]);
      a.x += l.x; a.y += l.y;
    }
    acc = a;
  }
  int p    = __builtin_amdgcn_readfirstlane(rowptr[node]);
  int dg   = __builtin_amdgcn_readfirstlane(deg[node]);
  int pend = p + dg;
  for (; p + 8 <= pend; p += 8) {
    int s0 = csr_src[p + 0], s1 = csr_src[p + 1], s2 = csr_src[p + 2], s3 = csr_src[p + 3];
    int s4 = csr_src[p + 4], s5 = csr_src[p + 5], s6 = csr_src[p + 6], s7 = csr_src[p + 7];
    __half2 g0 = nbr[(size_t)s0 * 64 + lane];   // 8 independent random 256B/wave gathers
    __half2 g1 = nbr[(size_t)s1 * 64 + lane];
    __half2 g2 = nbr[(size_t)s2 * 64 + lane];
    __half2 g3 = nbr[(size_t)s3 * 64 + lane];
    __half2 g4 = nbr[(size_t)s4 * 64 + lane];
    __half2 g5 = nbr[(size_t)s5 * 64 + lane];
    __half2 g6 = nbr[(size_t)s6 * 64 + lane];
    __half2 g7 = nbr[(size_t)s7 * 64 + lane];
    {   // edges 0-3: verbatim 4-edge body
      uint4 A0 = csr_a16[2 * (size_t)p + 0];
      uint4 A1 = csr_a16[2 * (size_t)p + 1];
      uint4 B0 = csr_a16[2 * (size_t)p + 2];
      uint4 B1 = csr_a16[2 * (size_t)p + 3];
      uint4 C0 = csr_a16[2 * (size_t)p + 4];
      uint4 C1 = csr_a16[2 * (size_t)p + 5];
      uint4 D0 = csr_a16[2 * (size_t)p + 6];
      uint4 D1 = csr_a16[2 * (size_t)p + 7];
      float t0x = bias.x, t0y = bias.y;
      float t1x = bias.x, t1y = bias.y;
      float t2x = bias.x, t2y = bias.y;
      float t3x = bias.x, t3y = bias.y;
      dot16(A0, A1, wA, wB, t0x, t0y);
      dot16(B0, B1, wA, wB, t1x, t1y);
      dot16(C0, C1, wA, wB, t2x, t2y);
      dot16(D0, D1, wA, wB, t3x, t3y);
      float2 f0 = __half22float2(g0);
      float2 f1 = __half22float2(g1);
      float2 f2 = __half22float2(g2);
      float2 f3 = __half22float2(g3);
      acc.x += fmaxf(f0.x + t0x, 0.f) + fmaxf(f1.x + t1x, 0.f)
             + fmaxf(f2.x + t2x, 0.f) + fmaxf(f3.x + t3x, 0.f);
      acc.y += fmaxf(f0.y + t0y, 0.f) + fmaxf(f1.y + t1y, 0.f)
             + fmaxf(f2.y + t2y, 0.f) + fmaxf(f3.y + t3y, 0.f);
    }
    {   // edges 4-7: verbatim 4-edge body
      uint4 A0 = csr_a16[2 * (size_t)p + 8];
      uint4 A1 = csr_a16[2 * (size_t)p + 9];
      uint4 B0 = csr_a16[2 * (size_t)p + 10];
      uint4 B1 = csr_a16[2 * (size_t)p + 11];
      uint4 C0 = csr_a16[2 * (size_t)p + 12];
      uint4 C1 = csr_a16[2 * (size_t)p + 13];
      uint4 D0 = csr_a16[2 * (size_t)p + 14];
      uint4 D1 = csr_a16[2 * (size_t)p + 15];
      float t0x = bias.x, t0y = bias.y;
      float t1x = bias.x, t1y = bias.y;
      float t2x = bias.x, t2y = bias.y;
      float t3x = bias.x, t3y = bias.y;
      dot16(A0, A1, wA, wB, t0x, t0y);
      dot16(B0, B1, wA, wB, t1x, t1y);
      dot16(C0, C1, wA, wB, t2x, t2y);
      dot16(D0, D1, wA, wB, t3x, t3y);
      float2 f0 = __half22float2(g4);
      float2 f1 = __half22float2(g5);
      float2 f2 = __half22float2(g6);
      float2 f3 = __half22float2(g7);
      acc.x += fmaxf(f0.x + t0x, 0.f) + fmaxf(f1.x + t1x, 0.f)
             + fmaxf(f2.x + t2x, 0.f) + fmaxf(f3.x + t3x, 0.f);
      acc.y += fmaxf(f0.y + t0y, 0.f) + fmaxf(f1.y + t1y, 0.f)
             + fmaxf(f2.y + t2y, 0.f) + fmaxf(f3.y + t3y, 0.f);
    }
  }
  for (; p + 4 <= pend; p += 4) {
    int s0 = csr_src[p + 0];
    int s1 = csr_src[p + 1];
    int s2 = csr_src[p + 2];
    int s3 = csr_src[p + 3];
    __half2 g0 = nbr[(size_t)s0 * 64 + lane];
    __half2 g1 = nbr[(size_t)s1 * 64 + lane];
    __half2 g2 = nbr[(size_t)s2 * 64 + lane];
    __half2 g3 = nbr[(size_t)s3 * 64 + lane];
    uint4 A0 = csr_a16[2 * (size_t)p + 0];
    uint4 A1 = csr_a16[2 * (size_t)p + 1];
    uint4 B0 = csr_a16[2 * (size_t)p + 2];
    uint4 B1 = csr_a16[2 * (size_t)p + 3];
    uint4 C0 = csr_a16[2 * (size_t)p + 4];
    uint4 C1 = csr_a16[2 * (size_t)p + 5];
    uint4 D0 = csr_a16[2 * (size_t)p + 6];
    uint4 D1 = csr_a16[2 * (size_t)p + 7];
    float t0x = bias.x, t0y = bias.y;
    float t1x = bias.x, t1y = bias.y;
    float t2x = bias.x, t2y = bias.y;
    float t3x = bias.x, t3y = bias.y;
    dot16(A0, A1, wA, wB, t0x, t0y);
    dot16(B0, B1, wA, wB, t1x, t1y);
    dot16(C0, C1, wA, wB, t2x, t2y);
    dot16(D0, D1, wA, wB, t3x, t3y);
    float2 f0 = __half22float2(g0);
    float2 f1 = __half22float2(g1);
    float2 f2 = __half22float2(g2);
    float2 f3 = __half22float2(g3);
    acc.x += fmaxf(f0.x + t0x, 0.f) + fmaxf(f1.x + t1x, 0.f)
           + fmaxf(f2.x + t2x, 0.f) + fmaxf(f3.x + t3x, 0.f);
    acc.y += fmaxf(f0.y + t0y, 0.f) + fmaxf(f1.y + t1y, 0.f)
           + fmaxf(f2.y + t2y, 0.f) + fmaxf(f3.y + t3y, 0.f);
  }
  for (; p + 2 <= pend; p += 2) {
    int s0 = csr_src[p];
    int s1 = csr_src[p + 1];
    __half2 g0 = nbr[(size_t)s0 * 64 + lane];
    __half2 g1 = nbr[(size_t)s1 * 64 + lane];
    uint4 A0 = csr_a16[2 * (size_t)p + 0];
    uint4 A1 = csr_a16[2 * (size_t)p + 1];
    uint4 B0 = csr_a16[2 * (size_t)p + 2];
    uint4 B1 = csr_a16[2 * (size_t)p + 3];
    float t0x = bias.x, t0y = bias.y;
    float t1x = bias.x, t1y = bias.y;
    dot16(A0, A1, wA, wB, t0x, t0y);
    dot16(B0, B1, wA, wB, t1x, t1y);
    float2 gf0 = __half22float2(g0);
    float2 gf1 = __half22float2(g1);
    acc.x += fmaxf(gf0.x + t0x, 0.f) + fmaxf(gf1.x + t1x, 0.f);
    acc.y += fmaxf(gf0.y + t0y, 0.f) + fmaxf(gf1.y + t1y, 0.f);
  }
  for (; p < pend; ++p) {
    int s = csr_src[p];
    __half2 g = nbr[(size_t)s * 64 + lane];
    uint4 A0 = csr_a16[2 * (size_t)p + 0];
    uint4 A1 = csr_a16[2 * (size_t)p + 1];
    float tx = bias.x, ty = bias.y;
    dot16(A0, A1, wA, wB, tx, ty);
    float2 gf = __half22float2(g);
    acc.x += fmaxf(gf.x + tx, 0.f);
    acc.y += fmaxf(gf.y + ty, 0.f);
  }
  return acc;
}

// Phase-2 MFMA on the block's 16-row sum tile; wave w owns ct {2w, 2w+1}.
__device__ __forceinline__ void update_tile_mfma(
    const __half2 (*lh)[68], const __half2 (*ll)[68],
    const uint4* __restrict__ Wph, const uint4* __restrict__ Wpl,
    int lane, int w, f32x4 acc2[2]) {
  int r16 = lane & 15;
  int kg  = lane >> 4;
  f16x8 a_hi[4], a_lo[4];
  const uint4* ph = (const uint4*)(&lh[r16][0]);
  const uint4* pl = (const uint4*)(&ll[r16][0]);
#pragma unroll
  for (int ks = 0; ks < 4; ++ks) {
    a_hi[ks] = __builtin_bit_cast(f16x8, ph[ks * 4 + kg]);
    a_lo[ks] = __builtin_bit_cast(f16x8, pl[ks * 4 + kg]);
  }
#pragma unroll
  for (int q = 0; q < 2; ++q) {
    acc2[q] = {0.f, 0.f, 0.f, 0.f};
    int ct = 2 * w + q;
#pragma unroll
    for (int ks = 0; ks < 4; ++ks) {
      f16x8 bh = __builtin_bit_cast(f16x8, Wph[(ks * 8 + ct) * 64 + lane]);
      f16x8 bl = __builtin_bit_cast(f16x8, Wpl[(ks * 8 + ct) * 64 + lane]);
      acc2[q] = __builtin_amdgcn_mfma_f32_16x16x32_f16(a_hi[ks], bh, acc2[q], 0, 0, 0);
      acc2[q] = __builtin_amdgcn_mfma_f32_16x16x32_f16(a_lo[ks], bh, acc2[q], 0, 0, 0);
      acc2[q] = __builtin_amdgcn_mfma_f32_16x16x32_f16(a_hi[ks], bl, acc2[q], 0, 0, 0);
    }
  }
}

// ================= fused gather+update (layers 0,1): writes h hi/lo to global =================
__global__ __launch_bounds__(256) void k_gather_update(
    const int* __restrict__ rowptr, const int* __restrict__ deg,
    const int* __restrict__ csr_src, const uint4* __restrict__ csr_a16,
    const __half2* __restrict__ nbr, const float* __restrict__ We,
    const float* __restrict__ be,
    const __half2* __restrict__ self_hi, const __half2* __restrict__ self_lo,
    const uint4* __restrict__ Wph, const uint4* __restrict__ Wpl,
    const float* __restrict__ b,
    __half* __restrict__ Ohi, __half* __restrict__ Olo) {
  __shared__ __half2 lds_hi[16][68];         // 68 half2/row = 272B stride (17x16B)
  __shared__ __half2 lds_lo[16][68];
  int lane = threadIdx.x & 63;
  int w = threadIdx.x >> 6;
  int c0 = 2 * lane;
  hv2 wA[8], wB[8];
#pragma unroll
  for (int j = 0; j < 8; ++j) {
    hv2 a, bq;
    a[0]  = (_Float16)We[(2 * j) * H + c0];
    a[1]  = (_Float16)We[(2 * j + 1) * H + c0];
    bq[0] = (_Float16)We[(2 * j) * H + c0 + 1];
    bq[1] = (_Float16)We[(2 * j + 1) * H + c0 + 1];
    wA[j] = a; wB[j] = bq;
  }
  float2 bias = ((const float2*)be)[lane];
  for (int j4 = 0; j4 < 4; ++j4) {
    int node = blockIdx.x * 16 + w * 4 + j4;
    float2 acc = gather_node(node, lane, rowptr, deg, csr_src, csr_a16,
                             nbr, self_hi, self_lo, bias, wA, wB);
    __half2 hh = __float22half2_rn(acc);
    float2 rf = __half22float2(hh);
    __half2 hl = __float22half2_rn(make_float2(acc.x - rf.x, acc.y - rf.y));
    lds_hi[w * 4 + j4][lane] = hh;
    lds_lo[w * 4 + j4][lane] = hl;
  }
  __syncthreads();
  f32x4 acc2[2];
  update_tile_mfma(lds_hi, lds_lo, Wph, Wpl, lane, w, acc2);
  int r16 = lane & 15;
  int kg  = lane >> 4;
  int colc = r16 * 8 + 2 * w;                // matrix cols colc, colc+1
  float b0 = b[colc], b1 = b[colc + 1];
#pragma unroll
  for (int r = 0; r < 4; ++r) {
    int grow = blockIdx.x * 16 + kg * 4 + r;
    float y0 = acc2[0][r] + b0;
    float y1 = acc2[1][r] + b1;
    y0 = y0 >= 0.f ? y0 : NEG * y0;
    y1 = y1 >= 0.f ? y1 : NEG * y1;
    __half2 h2 = __float22half2_rn(make_float2(y0, y1));
    float2 rf = __half22float2(h2);
    __half2 l2 = __float22half2_rn(make_float2(y0 - rf.x, y1 - rf.y));
    *(__half2*)(Ohi + (size_t)grow * H + colc) = h2;
    *(__half2*)(Olo + (size_t)grow * H + colc) = l2;
  }
}

// ================= fused gather+update+HEAD (layer 2): h stays in LDS; wave 0 runs the R10
// k_head wave body for this 16-row tile (bit-identical math); writes final fp32 out =================
__global__ __launch_bounds__(256) void k_gather_update_head(
    const int* __restrict__ rowptr, const int* __restrict__ deg,
    const int* __restrict__ csr_src, const uint4* __restrict__ csr_a16,
    const __half2* __restrict__ nbr, const float* __restrict__ We,
    const float* __restrict__ be,
    const __half2* __restrict__ self_hi, const __half2* __restrict__ self_lo,
    const uint4* __restrict__ Wph, const uint4* __restrict__ Wpl,
    const float* __restrict__ b,
    const __half* __restrict__ Shi,
    const uint4* __restrict__ WphH, const uint4* __restrict__ WplH,
    const float* __restrict__ bh, const float* __restrict__ gamma,
    const float* __restrict__ beta, float* __restrict__ out) {
  __shared__ __half2 lds_hi[16][68];
  __shared__ __half2 lds_lo[16][68];
  int lane = threadIdx.x & 63;
  int w = threadIdx.x >> 6;
  int c0 = 2 * lane;
  hv2 wA[8], wB[8];
#pragma unroll
  for (int j = 0; j < 8; ++j) {
    hv2 a, bq;
    a[0]  = (_Float16)We[(2 * j) * H + c0];
    a[1]  = (_Float16)We[(2 * j + 1) * H + c0];
    bq[0] = (_Float16)We[(2 * j) * H + c0 + 1];
    bq[1] = (_Float16)We[(2 * j + 1) * H + c0 + 1];
    wA[j] = a; wB[j] = bq;
  }
  float2 bias = ((const float2*)be)[lane];
  for (int j4 = 0; j4 < 4; ++j4) {
    int node = blockIdx.x * 16 + w * 4 + j4;
    float2 acc = gather_node(node, lane, rowptr, deg, csr_src, csr_a16,
                             nbr, self_hi, self_lo, bias, wA, wB);
    __half2 hh = __float22half2_rn(acc);
    float2 rf = __half22float2(hh);
    __half2 hl = __float22half2_rn(make_float2(acc.x - rf.x, acc.y - rf.y));
    lds_hi[w * 4 + j4][lane] = hh;
    lds_lo[w * 4 + j4][lane] = hl;
  }
  __syncthreads();
  f32x4 acc2[2];
  update_tile_mfma(lds_hi, lds_lo, Wph, Wpl, lane, w, acc2);
  __syncthreads();                           // all sum-tile reads done before overwrite
  {
    int r16 = lane & 15;
    int kg  = lane >> 4;
    int colc = r16 * 8 + 2 * w;
    float b0 = b[colc], b1 = b[colc + 1];
#pragma unroll
    for (int r = 0; r < 4; ++r) {
      int row = kg * 4 + r;
      float y0 = acc2[0][r] + b0;
      float y1 = acc2[1][r] + b1;
      y0 = y0 >= 0.f ? y0 : NEG * y0;
      y1 = y1 >= 0.f ? y1 : NEG * y1;
      __half2 h2 = __float22half2_rn(make_float2(y0, y1));
      float2 rf = __half22float2(h2);
      __half2 l2 = __float22half2_rn(make_float2(y0 - rf.x, y1 - rf.y));
      lds_hi[row][colc >> 1] = h2;           // h tile, [row][128 halves] layout
      lds_lo[row][colc >> 1] = l2;
    }
  }
  __syncthreads();
  if (threadIdx.x >= 64) return;             // phase 3: one wave = one R10 k_head wave body
  int r16 = lane & 15;
  int kg  = lane >> 4;
  int rowbase = blockIdx.x * 16;
  int arow = rowbase + r16;
  const uint4* ps = (const uint4*)(Shi + (size_t)arow * H);
  const uint4* ph = (const uint4*)(&lds_hi[r16][0]);
  const uint4* pl = (const uint4*)(&lds_lo[r16][0]);
  f16x8 a_hi[4], a_lo[4];
#pragma unroll
  for (int ks = 0; ks < 4; ++ks) {
    f16x8 s8 = __builtin_bit_cast(f16x8, ps[ks * 4 + kg]);
    f16x8 h8 = __builtin_bit_cast(f16x8, ph[ks * 4 + kg]);
    f16x8 l8 = __builtin_bit_cast(f16x8, pl[ks * 4 + kg]);
    f16x8 th, tl;
#pragma unroll
    for (int e = 0; e < 8; ++e) {
      float t = (float)s8[e] + (float)h8[e] + (float)l8[e];
      _Float16 hi = (_Float16)t;
      th[e] = hi;
      tl[e] = (_Float16)(t - (float)hi);
    }
    a_hi[ks] = th;
    a_lo[ks] = tl;
  }
  f32x4 acc[8];
#pragma unroll
  for (int ct = 0; ct < 8; ++ct) acc[ct] = {0.f, 0.f, 0.f, 0.f};
#pragma unroll
  for (int ct = 0; ct < 8; ++ct) {
#pragma unroll
    for (int ks = 0; ks < 4; ++ks) {
      f16x8 bhf = __builtin_bit_cast(f16x8, WphH[(ks * 8 + ct) * 64 + lane]);
      f16x8 blf = __builtin_bit_cast(f16x8, WplH[(ks * 8 + ct) * 64 + lane]);
      acc[ct] = __builtin_amdgcn_mfma_f32_16x16x32_f16(a_hi[ks], bhf, acc[ct], 0, 0, 0);
      acc[ct] = __builtin_amdgcn_mfma_f32_16x16x32_f16(a_lo[ks], bhf, acc[ct], 0, 0, 0);
      acc[ct] = __builtin_amdgcn_mfma_f32_16x16x32_f16(a_hi[ks], blf, acc[ct], 0, 0, 0);
    }
  }
  int colb = r16;
  float bias8[8];
#pragma unroll
  for (int ct = 0; ct < 8; ++ct) bias8[ct] = bh[ct * 16 + colb];
#pragma unroll
  for (int r = 0; r < 4; ++r) {
    float vals[8];
    float S = 0.f, S2 = 0.f;
#pragma unroll
    for (int ct = 0; ct < 8; ++ct) {
      float v = acc[ct][r] + bias8[ct];
      vals[ct] = v;
      S += v;
      S2 += v * v;
    }
#pragma unroll
    for (int off = 1; off < 16; off <<= 1) {
      S  += __shfl_xor(S, off);
      S2 += __shfl_xor(S2, off);
    }
    float mu  = S * (1.f / H);
    float var = S2 * (1.f / H) - mu * mu;
    float inv = rsqrtf(var + EPS);
    int grow = rowbase + kg * 4 + r;
#pragma unroll
    for (int ct = 0; ct < 8; ++ct)
      out[(size_t)grow * H + ct * 16 + colb] =
          (vals[ct] - mu) * inv * gamma[ct * 16 + colb] + beta[ct * 16 + colb];
  }
}

extern "C" void kernel_launch(void* const* d_in, const int* in_sizes, int n_in,
                              void* d_out, int out_size, void* d_ws, size_t ws_size,
                              hipStream_t stream) {
  const float* x         = (const float*)d_in[0];
  const float* edge_attr = (const float*)d_in[1];
  const int*   eidx      = (const int*)d_in[2];      // int32 (harness-converted)
  const float* W_node    = (const float*)d_in[3];
  const float* b_node    = (const float*)d_in[4];
  const float* W_edge    = (const float*)d_in[5];
  const float* b_edge    = (const float*)d_in[6];
  const float* W_conv    = (const float*)d_in[7];    // [3,128,128]
  const float* b_conv    = (const float*)d_in[8];    // [3,128]
  const float* W_head    = (const float*)d_in[9];
  const float* b_head    = (const float*)d_in[10];
  const float* gamma     = (const float*)d_in[11];
  const float* beta      = (const float*)d_in[12];
  float* out = (float*)d_out;

  // ---- workspace layout ----
  size_t S = (size_t)N * H;                  // 12.8M elems
  __half* hA_hi   = (__half*)d_ws;           // 25.6 MB (ws pair A)
  __half* hA_lo   = hA_hi + S;               // 25.6 MB
  __half* skip_hi = hA_lo + S;               // 25.6 MB
  uint4*  csr_a16 = (uint4*)(skip_hi + S);   // 51.2 MB (E x 32B)
  int*    csr_src = (int*)(csr_a16 + 2 * (size_t)E);  // 6.4 MB
  int*    deg     = csr_src + E;
  int*    excl    = deg + N;
  int*    rowptr  = excl + N;
  int*    cursor  = rowptr + N;
  int*    bsum    = cursor + N;
  int*    boff    = bsum + 512;
  __half* Wp_hi   = (__half*)(boff + 512);   // 4 mats x 16384 halfs = 128 KB
  __half* Wp_lo   = Wp_hi + 4 * 16384;       // 128 KB
  __half* hB_hi   = (__half*)out;            // pair B in d_out (dead before head writes out)
  __half* hB_lo   = hB_hi + S;

  const int eb = (E + 255) / 256;            // 6250

  // ---- weight pack + CSR build (once) ----
  k_pack_w<<<256, 256, 0, stream>>>(W_conv, W_head, Wp_hi, Wp_lo);
  k_zero<<<NB, 256, 0, stream>>>(deg, N);
  k_hist<<<eb, 256, 0, stream>>>(eidx, deg);
  k_scan_block<<<NB, 256, 0, stream>>>(deg, excl, bsum);
  k_scan_top<<<1, 512, 0, stream>>>(bsum, boff);
  k_scan_add<<<NB, 256, 0, stream>>>(excl, boff, rowptr, cursor);
  k_scatter<<<eb, 256, 0, stream>>>(eidx, edge_attr, cursor, csr_src, csr_a16);

  // ---- network ----
  k_node_linear<<<N / 32, 256, 0, stream>>>(x, W_node, b_node, skip_hi);

  // layer 0: skip -> B (d_out)
  k_gather_update<<<N / 16, 256, 0, stream>>>(rowptr, deg, csr_src, csr_a16,
      (const __half2*)skip_hi, W_edge, b_edge,
      (const __half2*)skip_hi, (const __half2*)nullptr,
      (const uint4*)(Wp_hi + 0 * (size_t)16384), (const uint4*)(Wp_lo + 0 * (size_t)16384),
      b_conv + 0 * H, hB_hi, hB_lo);
  // layer 1: B -> A (ws)
  k_gather_update<<<N / 16, 256, 0, stream>>>(rowptr, deg, csr_src, csr_a16,
      (const __half2*)hB_hi, W_edge, b_edge,
      (const __half2*)hB_hi, (const __half2*)hB_lo,
      (const uint4*)(Wp_hi + 1 * (size_t)16384), (const uint4*)(Wp_lo + 1 * (size_t)16384),
      b_conv + 1 * H, hA_hi, hA_lo);
  // layer 2 + head: A -> (LDS h) -> out (d_out; B is dead now)
  k_gather_update_head<<<N / 16, 256, 0, stream>>>(rowptr, deg, csr_src, csr_a16,
      (const __half2*)hA_hi, W_edge, b_edge,
      (const __half2*)hA_hi, (const __half2*)hA_lo,
      (const uint4*)(Wp_hi + 2 * (size_t)16384), (const uint4*)(Wp_lo + 2 * (size_t)16384),
      b_conv + 2 * H,
      skip_hi,
      (const uint4*)(Wp_hi + 3 * (size_t)16384), (const uint4*)(Wp_lo + 3 * (size_t)16384),
      b_head, gamma, beta, out);
}